// Round 11
// baseline (240.906 us; speedup 1.0000x reference)
//
#include <hip/hip_runtime.h>
#include <hip/hip_bf16.h>
#include <cstdint>

typedef unsigned short ushort_t;
typedef __attribute__((ext_vector_type(8))) short short8;
typedef __attribute__((ext_vector_type(4))) float floatx4;
typedef __attribute__((ext_vector_type(4))) unsigned short ushort4_t;

#define H_   16
#define DKV_ 64
#define DM_  1024
#define B_   2
#define NQ_  2048
#define NK_  2048

// fp32 -> bf16 round-to-nearest-even
__device__ __forceinline__ unsigned short f2bf(float f) {
  union { float f; unsigned int u; } v; v.f = f;
  unsigned int u = v.u;
  return (unsigned short)((u + 0x7fffu + ((u >> 16) & 1u)) >> 16);
}

// Trans ops via compiler-visible intrinsics (NOT inline asm) — R5-proven.
__device__ __forceinline__ float fexp2(float x) { return __builtin_amdgcn_exp2f(x); }
__device__ __forceinline__ float frcp(float x)  { return __builtin_amdgcn_rcpf(x); }

__device__ __forceinline__ floatx4 mfma16(short8 a, short8 b, floatx4 c) {
  return __builtin_amdgcn_mfma_f32_16x16x32_bf16(a, b, c, 0, 0, 0);
}

// async global->LDS, 16B per lane; LDS dest = wave-uniform base + lane*16
__device__ __forceinline__ void gload_lds16(const ushort_t* g, ushort_t* l) {
  __builtin_amdgcn_global_load_lds(
      (const __attribute__((address_space(1))) void*)g,
      (__attribute__((address_space(3))) void*)l, 16, 0, 0);
}

// lgkm-only barrier (R3-proven): drains LDS ops but NOT vmem, so prefetch
// global loads stay in flight across tiles. __syncthreads() would emit
// s_waitcnt vmcnt(0) and drain the gp prefetch every tile.
__device__ __forceinline__ void block_sync_lds() {
  asm volatile("s_waitcnt lgkmcnt(0)" ::: "memory");
  __builtin_amdgcn_s_barrier();
  __builtin_amdgcn_sched_barrier(0);
}

// ---------------- prep: fused cast_x + cast_wt (R10: one launch) ----------
// bid < 1536: X-cast role (identical math to R7-proven cast_x_kernel).
// bid >= 1536: W transpose-cast role (identical to cast_wt_kernel).
// Branch is block-uniform (bid), so the in-branch __syncthreads is safe.
__global__ __launch_bounds__(256) void prep_kernel(
    const float* __restrict__ q, const float* __restrict__ k,
    const float* __restrict__ v,
    const float* __restrict__ Wq, const float* __restrict__ Wk,
    const float* __restrict__ Wv,
    ushort_t* __restrict__ Xdst, ushort_t* __restrict__ WtAll)
{
  __shared__ ushort_t tile[32][33];
  const int bid = blockIdx.x;
  if (bid < 1536) {
    const int t = bid >> 9;                       // 0..2
    const float* src = (t == 0) ? q : (t == 1) ? k : v;
    ushort_t* d = Xdst + (size_t)t * 4096 * 1024;
    const int gid = (bid & 511) * 256 + threadIdx.x;
    #pragma unroll
    for (int u = 0; u < 8; u++) {
      const int i4 = u * 131072 + gid;
      floatx4 f = ((const floatx4*)src)[i4];
      ushort4_t o;
      #pragma unroll
      for (int e = 0; e < 4; e++) o[e] = f2bf(f[e]);
      *(ushort4_t*)&d[(size_t)i4 * 4] = o;
    }
  } else {
    const int b2 = bid - 1536;
    const int t = b2 >> 10;                       // 0..2
    const int rem = b2 & 1023;
    const float* W = (t == 0) ? Wq : (t == 1) ? Wk : Wv;
    ushort_t* Wt = WtAll + (size_t)t * 1024 * 1024;
    const int n0 = (rem & 31) * 32, k0 = (rem >> 5) * 32;
    const int tid = threadIdx.x, r = tid >> 3, c4 = (tid & 7) * 4;
    floatx4 f = *(const floatx4*)&W[(size_t)(k0 + r) * 1024 + n0 + c4];
    #pragma unroll
    for (int e = 0; e < 4; e++) tile[r][c4 + e] = f2bf(f[e]);
    __syncthreads();
    ushort4_t o;
    #pragma unroll
    for (int e = 0; e < 4; e++) o[e] = tile[c4 + e][r];
    *(ushort4_t*)&Wt[(size_t)(n0 + r) * 1024 + k0 + c4] = o;
  }
}

// ---------------- proj v4: 3-buf, 2-deep prefetch, counted-vmcnt barrier --
// R10 insight: proj v3's __syncthreads emitted vmcnt(0) each K-step,
// draining the just-issued next-step gloads — the SAME bug attn had before
// R9. v4 applies attn's proven fix: 3 LDS buffers, gloads issued 2 steps
// ahead (~2 step-bodies in flight >= L3 latency), end-of-step sync =
// s_waitcnt vmcnt(4) lgkmcnt(0) + s_barrier (vmcnt(4) keeps this step's 4
// prefetch gloads in flight; waits only the step-(t-1) batch the next read
// needs). Protocol: lgkmcnt(0) before barrier => all waves done reading
// buf[cur] before step t+1's gloads overwrite it; per-wave vmcnt drain
// before barrier => buf[(t+1)%3] fully written before cross-wave reads.
// Last 2 steps issue nothing => vmcnt(0) there (also pre-epilogue drain).
// LDS 48KB/block, 2 blocks/CU kept. ds_read/MFMA/epilogue byte-identical.
__global__ __launch_bounds__(256, 2) void proj_kernel2(
    const ushort_t* __restrict__ Xbf, const ushort_t* __restrict__ WtAll,
    const float* __restrict__ bq, const float* __restrict__ bk,
    const float* __restrict__ bv,
    ushort_t* __restrict__ Qb, ushort_t* __restrict__ Kb, ushort_t* __restrict__ Vt)
{
  const int mode = blockIdx.z;
  const ushort_t* X  = Xbf  + (size_t)mode * 4096 * 1024;
  const ushort_t* Wt = WtAll + (size_t)mode * 1024 * 1024;
  const float* bias  = (mode == 0) ? bq : (mode == 1) ? bk : bv;
  ushort_t* dst      = (mode == 0) ? Qb : (mode == 1) ? Kb : Vt;

  // buf i: A = SM + i*8192, B = SM + i*8192 + 4096   (shorts), i = 0..2
  __shared__ ushort_t SM[24576];

  const int tid = threadIdx.x, lane = tid & 63, wid = tid >> 6;
  const int c = lane & 15, g = lane >> 4;
  const int m0 = blockIdx.y * 128, n0 = blockIdx.x * 128;
  const int wm = wid & 1, wn = wid >> 1, mb = wm * 64, nb = wn * 64;
  const int srow = lane >> 2;
  const int schunk = (lane & 3) * 8;

  floatx4 acc[4][4];
  #pragma unroll
  for (int i = 0; i < 4; i++)
    #pragma unroll
    for (int j = 0; j < 4; j++) acc[i][j] = floatx4{0.f, 0.f, 0.f, 0.f};

  // prologue: stage steps 0 and 1 into bufs 0,1 (8 gloads/thread out)
  #pragma unroll
  for (int s = 0; s < 2; s++) {
    #pragma unroll
    for (int u = 0; u < 2; u++) {
      const int t = wid * 2 + u;
      gload_lds16(&X [(size_t)(m0 + t * 16 + srow) * 1024 + s * 32 + schunk],
                  &SM[s * 8192 + t * 512]);
      gload_lds16(&Wt[(size_t)(n0 + t * 16 + srow) * 1024 + s * 32 + schunk],
                  &SM[s * 8192 + 4096 + t * 512]);
    }
  }
  asm volatile("s_waitcnt vmcnt(4)" ::: "memory");   // step-0 batch done
  __builtin_amdgcn_s_barrier();
  __builtin_amdgcn_sched_barrier(0);

  int cur = 0;
  for (int step = 0; step < 32; step++) {
    // issue step+2 staging into the third buffer (2 bodies of cover)
    if (step + 2 < 32) {
      const int k2 = (step + 2) * 32;
      const int bufn = (step + 2) % 3;
      #pragma unroll
      for (int u = 0; u < 2; u++) {
        const int t = wid * 2 + u;
        gload_lds16(&X [(size_t)(m0 + t * 16 + srow) * 1024 + k2 + schunk],
                    &SM[bufn * 8192 + t * 512]);
        gload_lds16(&Wt[(size_t)(n0 + t * 16 + srow) * 1024 + k2 + schunk],
                    &SM[bufn * 8192 + 4096 + t * 512]);
      }
    }
    const ushort_t* SA = &SM[cur * 8192];
    const ushort_t* SB = &SM[cur * 8192 + 4096];
    short8 af[4], bfr[4];
    #pragma unroll
    for (int i = 0; i < 4; i++) af[i]  = *(const short8*)&SA[(mb + i * 16 + c) * 32 + g * 8];
    #pragma unroll
    for (int j = 0; j < 4; j++) bfr[j] = *(const short8*)&SB[(nb + j * 16 + c) * 32 + g * 8];
    #pragma unroll
    for (int i = 0; i < 4; i++)
      #pragma unroll
      for (int j = 0; j < 4; j++) acc[i][j] = mfma16(af[i], bfr[j], acc[i][j]);
    // counted-wait barrier: keep this step's 4 gloads in flight
    if (step + 2 < 32) {
      asm volatile("s_waitcnt vmcnt(4) lgkmcnt(0)" ::: "memory");
    } else {
      asm volatile("s_waitcnt vmcnt(0) lgkmcnt(0)" ::: "memory");
    }
    __builtin_amdgcn_s_barrier();
    __builtin_amdgcn_sched_barrier(0);
    cur = (cur == 2) ? 0 : cur + 1;
  }

  const float scale = (mode == 0) ? 0.18033688011112042f : 1.0f;
  ushort_t* EP = SM + wid * 2048;
  const int hh = (n0 + nb) >> 6;

  if (mode != 2) {
    for (int jj = 0; jj < 2; jj++) {
      #pragma unroll
      for (int jt = 0; jt < 2; jt++) {
        const int j = jj * 2 + jt;
        const float bb = bias[n0 + nb + j * 16 + c];
        #pragma unroll
        for (int i = 0; i < 4; i++)
          #pragma unroll
          for (int r = 0; r < 4; r++)
            EP[(i * 16 + g * 4 + r) * 32 + jt * 16 + c] =
                f2bf((acc[i][j][r] + bb) * scale);
      }
      #pragma unroll
      for (int u = 0; u < 8; u++) {
        const int rowl = u * 8 + (lane >> 3);
        ushort4_t vv = *(ushort4_t*)&EP[rowl * 32 + (lane & 7) * 4];
        const int rowg = m0 + mb + rowl;
        const int bb2 = rowg >> 11, nn = rowg & 2047;
        *(ushort4_t*)&dst[((size_t)(bb2 * H_ + hh) * NQ_ + nn) * DKV_ +
                          jj * 32 + (lane & 7) * 4] = vv;
      }
    }
  } else {
    const int bb2 = (m0 + mb) >> 11, nloc = (m0 + mb) & 2047;
    for (int j = 0; j < 4; j++) {
      const float bb = bias[n0 + nb + j * 16 + c];
      #pragma unroll
      for (int i = 0; i < 4; i++) {
        ushort4_t pk;
        #pragma unroll
        for (int r = 0; r < 4; r++) pk[r] = f2bf(acc[i][j][r] + bb);
        *(ushort4_t*)&EP[c * 72 + i * 16 + g * 4] = pk;
      }
      const int d0 = j * 16;
      #pragma unroll
      for (int u = 0; u < 2; u++) {
        const int coll = u * 8 + (lane >> 3);
        short8 vv = *(const short8*)&EP[coll * 72 + (lane & 7) * 8];
        *(short8*)&dst[((size_t)(bb2 * H_ + hh) * DKV_ + d0 + coll) * NK_ +
                       nloc + (lane & 7) * 8] = vv;
      }
    }
  }
}

// ---------------- proj fallback (R2/R5-proven) ----------------------------
constexpr int LDT = 40;
__global__ __launch_bounds__(256, 2) void proj_kernel_fb(
    const float* __restrict__ Xq, const float* __restrict__ Xk, const float* __restrict__ Xv,
    const float* __restrict__ Wq, const float* __restrict__ Wk, const float* __restrict__ Wv,
    const float* __restrict__ bq, const float* __restrict__ bk, const float* __restrict__ bv,
    ushort_t* __restrict__ Qb, ushort_t* __restrict__ Kb, ushort_t* __restrict__ Vt)
{
  const int mode = blockIdx.z;
  const float* X    = (mode == 0) ? Xq : (mode == 1) ? Xk : Xv;
  const float* W    = (mode == 0) ? Wq : (mode == 1) ? Wk : Wv;
  const float* bias = (mode == 0) ? bq : (mode == 1) ? bk : bv;
  ushort_t* dst     = (mode == 0) ? Qb : (mode == 1) ? Kb : Vt;

  __shared__ ushort_t Asm[128 * LDT];
  __shared__ ushort_t Bsm[128 * LDT];

  const int tid = threadIdx.x, lane = tid & 63, wid = tid >> 6;
  const int m0 = blockIdx.y * 128, n0 = blockIdx.x * 128;
  const int c = lane & 15, g = lane >> 4;
  const int wm = wid & 1, wn = wid >> 1, mb = wm * 64, nb = wn * 64;

  floatx4 acc[4][4];
  #pragma unroll
  for (int i = 0; i < 4; i++)
    #pragma unroll
    for (int j = 0; j < 4; j++) acc[i][j] = floatx4{0.f, 0.f, 0.f, 0.f};

  const int ar = tid >> 1, ah = tid & 1;
  const int bn = tid & 127, bh2 = tid >> 7;

  for (int k0 = 0; k0 < DM_; k0 += 32) {
    const floatx4* ap = (const floatx4*)(X + (size_t)(m0 + ar) * DM_ + k0 + ah * 16);
    floatx4 av0 = ap[0], av1 = ap[1], av2 = ap[2], av3 = ap[3];
    const float* wp = W + (size_t)(k0 + bh2 * 16) * 1024 + n0 + bn;
    float wv[16];
    #pragma unroll
    for (int j = 0; j < 16; j++) wv[j] = wp[j * 1024];
    short8 pa0, pa1, pb0, pb1;
    #pragma unroll
    for (int j = 0; j < 4; j++) {
      pa0[j] = (short)f2bf(av0[j]); pa0[4 + j] = (short)f2bf(av1[j]);
      pa1[j] = (short)f2bf(av2[j]); pa1[4 + j] = (short)f2bf(av3[j]);
    }
    #pragma unroll
    for (int j = 0; j < 8; j++) { pb0[j] = (short)f2bf(wv[j]); pb1[j] = (short)f2bf(wv[8 + j]); }
    __syncthreads();
    *(short8*)&Asm[ar * LDT + ah * 16]      = pa0;
    *(short8*)&Asm[ar * LDT + ah * 16 + 8]  = pa1;
    *(short8*)&Bsm[bn * LDT + bh2 * 16]     = pb0;
    *(short8*)&Bsm[bn * LDT + bh2 * 16 + 8] = pb1;
    __syncthreads();
    short8 af[4], bfr[4];
    #pragma unroll
    for (int i = 0; i < 4; i++) af[i]  = *(const short8*)&Asm[(mb + i * 16 + c) * LDT + g * 8];
    #pragma unroll
    for (int j = 0; j < 4; j++) bfr[j] = *(const short8*)&Bsm[(nb + j * 16 + c) * LDT + g * 8];
    #pragma unroll
    for (int i = 0; i < 4; i++)
      #pragma unroll
      for (int j = 0; j < 4; j++) acc[i][j] = mfma16(af[i], bfr[j], acc[i][j]);
  }
  #pragma unroll
  for (int j = 0; j < 4; j++) {
    const int col = n0 + nb + j * 16 + c;
    const float bv_ = bias[col];
    const int h = col >> 6, d = col & 63;
    #pragma unroll
    for (int i = 0; i < 4; i++)
      #pragma unroll
      for (int r = 0; r < 4; r++) {
        const int row = m0 + mb + i * 16 + g * 4 + r;
        const int b = row >> 11, n = row & 2047;
        float v = acc[i][j][r] + bv_;
        if (mode == 0) {
          v *= 0.18033688011112042f;
          dst[((size_t)(b * H_ + h) * NQ_ + n) * DKV_ + d] = f2bf(v);
        } else if (mode == 1) {
          dst[((size_t)(b * H_ + h) * NQ_ + n) * DKV_ + d] = f2bf(v);
        } else {
          dst[((size_t)(b * H_ + h) * DKV_ + d) * NK_ + n] = f2bf(v);
        }
      }
  }
}

// ---------------- attn v13 (R10 champion: 82.2us) — FROZEN ----------------
__global__ __launch_bounds__(512, 4) void attn_kernel(
    const ushort_t* __restrict__ Qb, const ushort_t* __restrict__ Kb,
    const ushort_t* __restrict__ Vt, const float* __restrict__ gp,
    float* __restrict__ out)
{
  __shared__ ushort_t Ks[2][64 * 72];
  __shared__ ushort_t Vs[2][64 * 72];
  __shared__ ushort_t Pl[8][16 * 72];

  constexpr int NT = NK_ / 64;                    // 32 tiles

  const int tid = threadIdx.x, lane = tid & 63, wid = tid >> 6;  // wid 0..7
  const int c = lane & 15, g = lane >> 4;
  const int h = blockIdx.x, b = blockIdx.z;       // h fastest: gp L2 locality
  const int bh = b * H_ + h;
  const int qw = blockIdx.y * 128 + wid * 16;

  const ushort_t* Qp = Qb + (size_t)bh * NQ_ * DKV_;
  const ushort_t* Kp = Kb + (size_t)bh * NK_ * DKV_;
  const ushort_t* Vp = Vt + (size_t)bh * DKV_ * NK_;
  const float* gpp = gp + (size_t)b * NQ_ * NK_ + (size_t)qw * NK_;
  ushort_t* Pw = Pl[wid];

  const int gx16 = (g >> 1) << 4;                 // write-side granule XOR
  const int prd  = g ^ (((c >> 3) & 1) << 1);     // read-side swizzled g

  // cooperative staging: 512 threads cover 64x64, 1 chunk each for K and V
  const int srow = tid >> 3;                      // 0..63
  const int scol = (tid & 7) * 8;                 // 0..56

  // Q fragments resident (pre-scaled by log2(e)/8)
  short8 qf[2];
  #pragma unroll
  for (int kc = 0; kc < 2; kc++)
    qf[kc] = *(const short8*)&Qp[(qw + c) * DKV_ + kc * 32 + g * 8];

  // stage tile 0; gp(0) into gpA
  *(short8*)&Ks[0][srow * 72 + scol] = *(const short8*)&Kp[(size_t)srow * DKV_ + scol];
  *(short8*)&Vs[0][srow * 72 + scol] = *(const short8*)&Vp[(size_t)srow * NK_ + scol];
  float gpA[4][4], gpB[4][4];
  #pragma unroll
  for (int r = 0; r < 4; r++) {
    const float* gq = gpp + (size_t)(g * 4 + r) * NK_ + c;
    #pragma unroll
    for (int jk = 0; jk < 4; jk++) gpA[jk][r] = gq[jk * 16];
  }
  __syncthreads();   // one-time full drain

  floatx4 o[4];
  float l[4];
  #pragma unroll
  for (int jd = 0; jd < 4; jd++) o[jd] = floatx4{0.f, 0.f, 0.f, 0.f};
  #pragma unroll
  for (int r = 0; r < 4; r++) l[r] = 0.f;

  // body: compute tile T from LDS[CUR], gate with GPC (loaded last tile);
  // issue stage(T+1) then gp(T+1)->GPN; commit stage; lgkm-only barrier.
#define ATTN_BODY(T, CUR, GPC, GPN)                                          \
  {                                                                          \
    const int t_ = (T);                                                      \
    const int k0 = t_ * 64;                                                  \
    const bool hn = (t_ + 1) < NT;                                           \
    /* stage loads FIRST (older in vmem queue than gp) */                    \
    short8 knx, vnx;                                                         \
    if (hn) {                                                                \
      const int k1 = k0 + 64;                                                \
      knx = *(const short8*)&Kp[(size_t)(k1 + srow) * DKV_ + scol];          \
      vnx = *(const short8*)&Vp[(size_t)srow * NK_ + k1 + scol];             \
    }                                                                        \
    /* gp(t+1) into GPN (consumed next tile; survives the lgkm barrier) */   \
    if (hn) {                                                                \
      const int k1 = k0 + 64;                                                \
      _Pragma("unroll")                                                      \
      for (int r = 0; r < 4; r++) {                                          \
        const float* gq = gpp + (size_t)(g * 4 + r) * NK_ + k1 + c;          \
        _Pragma("unroll")                                                    \
        for (int jk = 0; jk < 4; jk++) GPN[jk][r] = gq[jk * 16];             \
      }                                                                      \
    }                                                                        \
    /* S = Q K^T (log2 domain), K from LDS */                                \
    floatx4 s_[4];                                                           \
    _Pragma("unroll")                                                        \
    for (int jk = 0; jk < 4; jk++) s_[jk] = floatx4{0.f, 0.f, 0.f, 0.f};     \
    __builtin_amdgcn_s_setprio(1);                                           \
    _Pragma("unroll")                                                        \
    for (int jk = 0; jk < 4; jk++)                                           \
      _Pragma("unroll")                                                      \
      for (int kc = 0; kc < 2; kc++) {                                       \
        short8 kf = *(const short8*)&Ks[CUR][(jk * 16 + c) * 72 + kc * 32 + g * 8]; \
        s_[jk] = mfma16(qf[kc], kf, s_[jk]);                                 \
      }                                                                      \
    __builtin_amdgcn_s_setprio(0);                                           \
    /* p = exp2(s); per-lane l; gate by GPC; P -> LDS (swizzled) */          \
    _Pragma("unroll")                                                        \
    for (int jk = 0; jk < 4; jk++) {                                         \
      const int colw = (jk << 4) ^ gx16;                                     \
      _Pragma("unroll")                                                      \
      for (int r = 0; r < 4; r++) {                                          \
        const float p = fexp2(s_[jk][r]);                                    \
        l[r] += p;                                                           \
        Pw[(g * 4 + r) * 72 + colw + c] = f2bf(p * GPC[jk][r]);              \
      }                                                                      \
    }                                                                        \
    /* PV: A = P rows (swizzled read), B = V from LDS */                     \
    __builtin_amdgcn_s_setprio(1);                                           \
    _Pragma("unroll")                                                        \
    for (int kc = 0; kc < 2; kc++) {                                         \
      short8 af = *(const short8*)&Pw[c * 72 + kc * 32 + prd * 8];           \
      _Pragma("unroll")                                                      \
      for (int jd = 0; jd < 4; jd++) {                                       \
        short8 vf = *(const short8*)&Vs[CUR][(jd * 16 + c) * 72 + kc * 32 + g * 8]; \
        o[jd] = mfma16(af, vf, o[jd]);                                       \
      }                                                                      \
    }                                                                        \
    __builtin_amdgcn_s_setprio(0);                                           \
    /* commit tile t+1 (vmcnt auto-counted on knx/vnx; gp stays in flight)*/ \
    if (hn) {                                                                \
      *(short8*)&Ks[(CUR) ^ 1][srow * 72 + scol] = knx;                      \
      *(short8*)&Vs[(CUR) ^ 1][srow * 72 + scol] = vnx;                      \
    }                                                                        \
    block_sync_lds();                                                        \
  }

  for (int tt = 0; tt < NT; tt += 2) {
    ATTN_BODY(tt,     0, gpA, gpB)
    ATTN_BODY(tt + 1, 1, gpB, gpA)
  }
#undef ATTN_BODY

  // l-reduction across the 16 c-lanes (once per kernel)
  float invl[4];
  #pragma unroll
  for (int r = 0; r < 4; r++) {
    float rs = l[r];
    rs += __shfl_xor(rs, 1);
    rs += __shfl_xor(rs, 2);
    rs += __shfl_xor(rs, 4);
    rs += __shfl_xor(rs, 8);
    invl[r] = frcp(rs);
  }
  #pragma unroll
  for (int jd = 0; jd < 4; jd++)
    #pragma unroll
    for (int r = 0; r < 4; r++) {
      const int row = qw + g * 4 + r;
      out[(size_t)(b * NQ_ + row) * 1024 + h * 64 + jd * 16 + c] =
          o[jd][r] * invl[r];
    }
}

extern "C" void kernel_launch(void* const* d_in, const int* in_sizes, int n_in,
                              void* d_out, int out_size, void* d_ws, size_t ws_size,
                              hipStream_t stream) {
  const float* queries = (const float*)d_in[0];
  const float* keys    = (const float*)d_in[1];
  const float* values  = (const float*)d_in[2];
  const float* gp      = (const float*)d_in[3];
  // d_in[4] attention_mask: intentionally unused (reference discards it)
  const float* Wq = (const float*)d_in[5];
  const float* bq = (const float*)d_in[6];
  const float* Wk = (const float*)d_in[7];
  const float* bk = (const float*)d_in[8];
  const float* Wv = (const float*)d_in[9];
  const float* bv = (const float*)d_in[10];

  const size_t SZ_QKV = (size_t)3 * B_ * H_ * NQ_ * DKV_;  // shorts
  const size_t SZ_X   = (size_t)3 * 4096 * 1024;
  const size_t SZ_W   = (size_t)3 * 1024 * 1024;
  const size_t NEED   = (SZ_QKV + SZ_X + SZ_W) * sizeof(ushort_t);

  ushort_t* Qb = (ushort_t*)d_ws;                       // [B,H,NQ,64] bf16, pre-scaled
  ushort_t* Kb = Qb + (size_t)B_ * H_ * NQ_ * DKV_;     // [B,H,NK,64] bf16
  ushort_t* Vt = Kb + (size_t)B_ * H_ * NK_ * DKV_;     // [B,H,64,NK] bf16
  float* out = (float*)d_out;

  if (ws_size >= NEED) {
    ushort_t* Xbf = Qb + SZ_QKV;
    ushort_t* Wt  = Xbf + SZ_X;
    prep_kernel<<<dim3(4608), 256, 0, stream>>>(
        queries, keys, values, Wq, Wk, Wv, Xbf, Wt);
    proj_kernel2<<<dim3(8, 32, 3), 256, 0, stream>>>(
        Xbf, Wt, bq, bk, bv, Qb, Kb, Vt);
  } else {
    proj_kernel_fb<<<dim3(8, 32, 3), 256, 0, stream>>>(
        queries, keys, values, Wq, Wk, Wv, bq, bk, bv, Qb, Kb, Vt);
  }
  attn_kernel<<<dim3(H_, NQ_ / 128, B_), 512, 0, stream>>>(Qb, Kb, Vt, gp, out);
}